// Round 5
// baseline (529.420 us; speedup 1.0000x reference)
//
#include <hip/hip_runtime.h>

// ---------------------------------------------------------------------------
// EdgeUpdaterFrameDiff: x_down proj -> outer-concat edge bias -> 2-layer MLP
// with relu + residual -> out proj -> LayerNorm.  bf16 MFMA implementation.
//
// R8-resubmit: identical to R8 (round-4 container failure was infra, not the
// kernel — no pytest/absmax output). Changes vs R7: (1) #pragma unroll 6 on
// the three MFMA K-loops (was 2). Theory: loops are exposed-L2-latency bound
// (R7 refuted the LDS A-read theory: halving A-reads changed nothing). 6-iter
// chunks put 12 B-loads in flight (~48 VGPR) -> compiler's counted-vmcnt
// scheduling hides ~200cy L2 latency under MFMA issue. Register budget ~135 <
// 170 hard cap (12-wave block needs 3 waves/SIMD). R5 lesson: no min-waves
// launch_bounds arg (caused 84-VGPR cap + spills). (2) k_xdown + k_wswz3
// merged into one k_prep launch (R4->R7 showed launch-count cuts pay ~30us).
// Spill canaries: VGPR_Count <= ~150, WRITE_SIZE == 131072 KB.
// ---------------------------------------------------------------------------

using bf16x8 = __attribute__((ext_vector_type(8))) __bf16;
using f32x16 = __attribute__((ext_vector_type(16))) float;

#define LPAD 392            // bf16 row stride for 384-wide LDS tiles (16B aligned)
#define OPAD 132            // f32 row stride for 128-wide LN staging

__device__ inline unsigned short f2bf(float f) {
    union { float f; unsigned int u; } v; v.f = f;
    unsigned int r = v.u + 0x7fffu + ((v.u >> 16) & 1u);   // RNE
    return (unsigned short)(r >> 16);
}
__device__ inline float bf2f(unsigned short h) {
    union { unsigned int u; float f; } v; v.u = ((unsigned int)h) << 16;
    return v.f;
}

// --------------- merged prep: xdown (blocks 0..255) + wswz (256..423) ------
// xdown: 2 rows/block, 256 thr (half = row, t = col). wswz: R7 body.
__global__ void k_prep(const float* __restrict__ x, const float* __restrict__ Wd,
                       const float* __restrict__ bd, unsigned short* __restrict__ xd,
                       const float* __restrict__ W1, const float* __restrict__ W2,
                       const float* __restrict__ Wo,
                       unsigned short* __restrict__ W1s, unsigned short* __restrict__ W2s,
                       unsigned short* __restrict__ Wos) {
    if (blockIdx.x < 256) {
        __shared__ float sx[2][256];
        const int half = threadIdx.x >> 7;     // 0/1 -> row
        const int t = threadIdx.x & 127;       // output col
        const int i = blockIdx.x * 2 + half;   // row 0..511
        if (t < 64) *(float4*)&sx[half][t * 4] = *(const float4*)&x[i * 256 + t * 4];
        __syncthreads();
        const float* wr = &Wd[t * 256];
        const float* xr = sx[half];
        float sum = 0.f;
#pragma unroll 8
        for (int k = 0; k < 256; k += 4) {
            float4 wv = *(const float4*)&wr[k];
            float4 xv = *(const float4*)&xr[k];
            sum += wv.x * xv.x + wv.y * xv.y + wv.z * xv.z + wv.w * xv.w;
        }
        xd[i * 128 + t] = f2bf(sum + bd[t]);
    } else {
        const int b = blockIdx.x - 256;
        const float* W; unsigned short* dst; int c;
        if (b < 72)       { W = W1; dst = W1s; c = b * 256 + threadIdx.x; }
        else if (b < 144) { W = W2; dst = W2s; c = (b - 72) * 256 + threadIdx.x; }
        else              { W = Wo; dst = Wos; c = (b - 144) * 256 + threadIdx.x; }
        int lane = c & 63;
        int ks = (c >> 6) % 24;
        int nt = c / (24 * 64);
        int n = nt * 32 + (lane & 31);
        int k0 = ks * 16 + ((lane >> 5) << 3);
        const float* src = &W[n * 384 + k0];
        unsigned short tmp[8];
#pragma unroll
        for (int j = 0; j < 8; ++j) tmp[j] = f2bf(src[j]);
        *(uint4*)&dst[(size_t)c * 8] = *(const uint4*)tmp;
    }
}

// ------------------------------- main kernel -------------------------------
__global__ __launch_bounds__(768) void edge_main(
    const float* __restrict__ z, const unsigned short* __restrict__ xd,
    const unsigned short* __restrict__ W1s, const unsigned short* __restrict__ W2s,
    const unsigned short* __restrict__ Wos,
    const float* __restrict__ b1, const float* __restrict__ b2,
    const float* __restrict__ bo, const float* __restrict__ gamma,
    const float* __restrict__ beta, float* __restrict__ out)
{
    extern __shared__ char smem[];
    unsigned short* sA = (unsigned short*)smem;                    // z_in / residual, 64*LPAD bf16
    unsigned short* sH = (unsigned short*)(smem + 64 * LPAD * 2);  // h1
    float* sO = (float*)sH;                                        // overlaid: LN staging 64*OPAD f32

    const int tid = threadIdx.x;
    const int lane = tid & 63;
    const int w = tid >> 6;                   // wave 0..11
    const int i = blockIdx.x >> 3;            // 0..511   [R1 decode]
    const int j0 = (blockIdx.x & 7) << 6;     // 0..448

    const int arow = lane & 31;
    const int kof = (lane >> 5) << 3;   // 0 or 8
    const int half2 = (lane >> 5) << 2; // 0 or 4 (C/D row offset)

    // R7 work split for L1/L2: row-half + two N-tiles per wave
    const int mt  = w & 1;              // row half 0/1 -> rows mt*32..mt*32+31
    const int ng  = w >> 1;             // 0..5 -> N-tiles ng and ng+6
    const int rbase = mt << 5;

    // ---- stage z_in = [xd[i] | xd[j] | z[i,j,:]] as bf16 ----  [R1/R4 verbatim]
    for (int c = tid; c < 64 * 16; c += 768) {
        int r = c >> 4, cc = (c & 15) << 3;
        *(uint4*)&sA[r * LPAD + cc] = *(const uint4*)&xd[i * 128 + cc];
        *(uint4*)&sA[r * LPAD + 128 + cc] = *(const uint4*)&xd[(j0 + r) * 128 + cc];
    }
    for (int c = tid; c < 64 * 32; c += 768) {
        int r = c >> 5, cc = (c & 31) << 2;
        float4 v = *(const float4*)&z[((size_t)((i << 9) + j0 + r) << 7) + cc];
        ushort4 o;
        o.x = f2bf(v.x); o.y = f2bf(v.y); o.z = f2bf(v.z); o.w = f2bf(v.w);
        *(ushort4*)&sA[r * LPAD + 256 + cc] = o;
    }
    __syncthreads();

    // ===== layer 1: h1 = relu(z_in @ W1^T + b1) =====
    // wave w -> rows rbase..rbase+31, N-tiles ng and ng+6 (A-frag shared).
    {
        f32x16 acc0 = {}, acc1 = {};
#pragma unroll 6
        for (int ks = 0; ks < 24; ++ks) {
            int k = ks * 16 + kof;
            bf16x8 a  = *(const bf16x8*)&sA[(rbase + arow) * LPAD + k];
            bf16x8 b0 = *(const bf16x8*)&W1s[(size_t)(((ng    ) * 24 + ks) * 64 + lane) * 8];
            bf16x8 bb1 = *(const bf16x8*)&W1s[(size_t)(((ng + 6) * 24 + ks) * 64 + lane) * 8];
            acc0 = __builtin_amdgcn_mfma_f32_32x32x16_bf16(a, b0, acc0, 0, 0, 0);
            acc1 = __builtin_amdgcn_mfma_f32_32x32x16_bf16(a, bb1, acc1, 0, 0, 0);
        }
        const int colA = ng * 32 + arow;
        const int colB = (ng + 6) * 32 + arow;
        const float biasA = b1[colA];
        const float biasB = b1[colB];
#pragma unroll
        for (int rg = 0; rg < 16; ++rg) {
            int rr = rbase + half2 + (rg & 3) + ((rg >> 2) << 3);
            float v0 = acc0[rg] + biasA; v0 = v0 > 0.f ? v0 : 0.f;
            float v1 = acc1[rg] + biasB; v1 = v1 > 0.f ? v1 : 0.f;
            sH[rr * LPAD + colA] = f2bf(v0);
            sH[rr * LPAD + colB] = f2bf(v1);
        }
    }
    __syncthreads();

    // ===== layer 2: s = relu(h1 @ W2^T + b2) + z_in  (in place in sA) =====
    {
        f32x16 acc0 = {}, acc1 = {};
#pragma unroll 6
        for (int ks = 0; ks < 24; ++ks) {
            int k = ks * 16 + kof;
            bf16x8 a  = *(const bf16x8*)&sH[(rbase + arow) * LPAD + k];
            bf16x8 b0 = *(const bf16x8*)&W2s[(size_t)(((ng    ) * 24 + ks) * 64 + lane) * 8];
            bf16x8 bb1 = *(const bf16x8*)&W2s[(size_t)(((ng + 6) * 24 + ks) * 64 + lane) * 8];
            acc0 = __builtin_amdgcn_mfma_f32_32x32x16_bf16(a, b0, acc0, 0, 0, 0);
            acc1 = __builtin_amdgcn_mfma_f32_32x32x16_bf16(a, bb1, acc1, 0, 0, 0);
        }
        const int colA = ng * 32 + arow;
        const int colB = (ng + 6) * 32 + arow;
        const float biasA = b2[colA];
        const float biasB = b2[colB];
#pragma unroll
        for (int rg = 0; rg < 16; ++rg) {
            int rr = rbase + half2 + (rg & 3) + ((rg >> 2) << 3);
            float v0 = acc0[rg] + biasA; v0 = v0 > 0.f ? v0 : 0.f;
            float v1 = acc1[rg] + biasB; v1 = v1 > 0.f ? v1 : 0.f;
            float r0 = bf2f(sA[rr * LPAD + colA]);
            float r1 = bf2f(sA[rr * LPAD + colB]);
            sA[rr * LPAD + colA] = f2bf(v0 + r0);
            sA[rr * LPAD + colB] = f2bf(v1 + r1);
        }
    }
    __syncthreads();

    // ===== layer 3: out = s @ Wo^T + bo; waves 0..7 -> (mt,nt) units =====
    // [R4 verbatim apart from unroll]
    if (w < 8) {
        const int mt3 = w >> 2;           // M-tile 0/1
        const int nt3 = w & 3;            // N-tile 0..3
        f32x16 acc = {};
#pragma unroll 6
        for (int ks = 0; ks < 24; ++ks) {
            int k = ks * 16 + kof;
            bf16x8 a0 = *(const bf16x8*)&sA[(arow + mt3 * 32) * LPAD + k];
            bf16x8 b = *(const bf16x8*)&Wos[(size_t)((nt3 * 24 + ks) * 64 + lane) * 8];
            acc = __builtin_amdgcn_mfma_f32_32x32x16_bf16(a0, b, acc, 0, 0, 0);
        }
        int col = nt3 * 32 + arow;
        float bias = bo[col];
#pragma unroll
        for (int rg = 0; rg < 16; ++rg) {
            int rr = mt3 * 32 + half2 + (rg & 3) + ((rg >> 2) << 3);
            sO[rr * OPAD + col] = acc[rg] + bias;
        }
    }
    __syncthreads();

    // ===================== LayerNorm + store  [R1/R4 verbatim] ==============
    if (tid < 256) {
        const int r = tid >> 2;       // row 0..63
        const int q = tid & 3;        // quarter
        float s = 0.f, ss = 0.f;
#pragma unroll
        for (int ii = 0; ii < 32; ++ii) {
            float v = sO[r * OPAD + q + (ii << 2)];
            s += v; ss += v * v;
        }
        s += __shfl_xor(s, 1);  ss += __shfl_xor(ss, 1);
        s += __shfl_xor(s, 2);  ss += __shfl_xor(ss, 2);
        const float mean = s * (1.f / 128.f);
        const float var = ss * (1.f / 128.f) - mean * mean;
        const float rstd = rsqrtf(var + 1e-5f);
        float* po = &out[((size_t)((i << 9) + j0 + r)) << 7];
#pragma unroll
        for (int ii = 0; ii < 8; ++ii) {
            int c0 = q * 32 + (ii << 2);
            float4 v = *(const float4*)&sO[r * OPAD + c0];
            float4 g = *(const float4*)&gamma[c0];
            float4 bb = *(const float4*)&beta[c0];
            float4 o;
            o.x = (v.x - mean) * rstd * g.x + bb.x;
            o.y = (v.y - mean) * rstd * g.y + bb.y;
            o.z = (v.z - mean) * rstd * g.z + bb.z;
            o.w = (v.w - mean) * rstd * g.w + bb.w;
            *(float4*)&po[c0] = o;
        }
    }
}

extern "C" void kernel_launch(void* const* d_in, const int* in_sizes, int n_in,
                              void* d_out, int out_size, void* d_ws, size_t ws_size,
                              hipStream_t stream) {
    const float* x     = (const float*)d_in[0];
    const float* z     = (const float*)d_in[1];
    const float* Wd    = (const float*)d_in[2];
    const float* bd    = (const float*)d_in[3];
    const float* W1    = (const float*)d_in[4];
    const float* b1    = (const float*)d_in[5];
    const float* W2    = (const float*)d_in[6];
    const float* b2    = (const float*)d_in[7];
    const float* Wo    = (const float*)d_in[8];
    const float* bo    = (const float*)d_in[9];
    const float* gamma = (const float*)d_in[10];
    const float* beta  = (const float*)d_in[11];
    float* out = (float*)d_out;

    unsigned short* xd  = (unsigned short*)d_ws;                       // 512*128*2   = 131072
    unsigned short* W1s = (unsigned short*)((char*)d_ws + 131072);     // 294912
    unsigned short* W2s = (unsigned short*)((char*)d_ws + 425984);     // 294912
    unsigned short* Wos = (unsigned short*)((char*)d_ws + 720896);     // 98304

    hipLaunchKernelGGL(k_prep, dim3(424), dim3(256), 0, stream,
                       x, Wd, bd, xd, W1, W2, Wo, W1s, W2s, Wos);

    const size_t smem = (size_t)(64 * LPAD * 2) * 2;   // sA + sH (sO overlaid) = 100352 B
    hipLaunchKernelGGL(edge_main, dim3(4096), dim3(768), smem, stream,
                       z, xd, W1s, W2s, Wos, b1, b2, bo, gamma, beta, out);
}